// Round 1
// baseline (358.551 us; speedup 1.0000x reference)
//
#include <hip/hip_runtime.h>

typedef __attribute__((ext_vector_type(8))) short short8;
typedef __attribute__((ext_vector_type(4))) float f32x4;

#define MFMA_BF16(A_, B_, C_) __builtin_amdgcn_mfma_f32_16x16x32_bf16((A_), (B_), (C_), 0, 0, 0)

__device__ __forceinline__ unsigned short f2bf(float f) {
  unsigned int u = __builtin_bit_cast(unsigned int, f);
  return (unsigned short)((u + 0x7FFFu + ((u >> 16) & 1u)) >> 16);
}

// ---------------------------------------------------------------- convert
#define NX (8192 * 1024)
#define NW (1024 * 1024)

__global__ void convert_k(const float* __restrict__ x,
                          const float* __restrict__ wq, const float* __restrict__ wk,
                          const float* __restrict__ wv, const float* __restrict__ wo,
                          unsigned short* __restrict__ xb,
                          unsigned short* __restrict__ wqkv,
                          unsigned short* __restrict__ wob) {
  size_t i = ((size_t)blockIdx.x * blockDim.x + threadIdx.x) * 4;
  const float* sp;
  unsigned short* dp;
  if (i < (size_t)NX) {
    sp = x + i; dp = xb + i;
  } else {
    size_t j = i - NX;
    if (j < (size_t)NW)               { sp = wq + j;            dp = wqkv + j; }
    else if (j < (size_t)(2 * NW))    { sp = wk + (j - NW);     dp = wqkv + j; }
    else if (j < (size_t)(3 * NW))    { sp = wv + (j - 2 * NW); dp = wqkv + j; }
    else                              { sp = wo + (j - 3 * NW); dp = wob + (j - 3 * NW); }
  }
  float4 v = *(const float4*)sp;
  ushort4 o;
  o.x = f2bf(v.x); o.y = f2bf(v.y); o.z = f2bf(v.z); o.w = f2bf(v.w);
  *(ushort4*)dp = o;
}

// ---------------------------------------------------------------- GEMM1: QKV projection
// A = x_bf16 [8192][1024], Bw = [Wq;Wk;Wv] bf16 [3072][1024] (B^T layout)
// writes Q,K -> [bh][s][64], V -> transposed [bh][64][s]
__global__ __launch_bounds__(256, 2) void gemm_qkv_k(
    const unsigned short* __restrict__ A, const unsigned short* __restrict__ Bw,
    const float* __restrict__ bq, const float* __restrict__ bk, const float* __restrict__ bv,
    unsigned short* __restrict__ qb, unsigned short* __restrict__ kb,
    unsigned short* __restrict__ vtb) {
  const int K = 1024;
  __shared__ __align__(16) unsigned short lA[128 * 32];
  __shared__ __align__(16) unsigned short lB[128 * 32];
  const int tid = threadIdx.x;
  const int lane = tid & 63;
  const int w = tid >> 6;
  const int wm = w >> 1, wn = w & 1;
  const int m0 = blockIdx.x * 128, n0 = blockIdx.y * 128;
  const int l15 = lane & 15, lg = lane >> 4;

  const f32x4 zf = {0.0f, 0.0f, 0.0f, 0.0f};
  f32x4 acc[4][4];
#pragma unroll
  for (int mi = 0; mi < 4; ++mi)
#pragma unroll
    for (int ni = 0; ni < 4; ++ni) acc[mi][ni] = zf;

  const int c0 = tid, c1 = tid + 256;
  const int r0 = c0 >> 2, k0c = (c0 & 3) * 8;
  const int r1 = c1 >> 2, k1c = (c1 & 3) * 8;
  const unsigned short* ga0 = A + (size_t)(m0 + r0) * K + k0c;
  const unsigned short* ga1 = A + (size_t)(m0 + r1) * K + k1c;
  const unsigned short* gb0 = Bw + (size_t)(n0 + r0) * K + k0c;
  const unsigned short* gb1 = Bw + (size_t)(n0 + r1) * K + k1c;

  for (int kt = 0; kt < K; kt += 32) {
    short8 va0 = *(const short8*)(ga0 + kt);
    short8 va1 = *(const short8*)(ga1 + kt);
    short8 vb0 = *(const short8*)(gb0 + kt);
    short8 vb1 = *(const short8*)(gb1 + kt);
    __syncthreads();
    *(short8*)&lA[c0 * 8] = va0;
    *(short8*)&lA[c1 * 8] = va1;
    *(short8*)&lB[c0 * 8] = vb0;
    *(short8*)&lB[c1 * 8] = vb1;
    __syncthreads();
    short8 af[4], bf[4];
#pragma unroll
    for (int mi = 0; mi < 4; ++mi)
      af[mi] = *(const short8*)&lA[(wm * 64 + mi * 16 + l15) * 32 + lg * 8];
#pragma unroll
    for (int ni = 0; ni < 4; ++ni)
      bf[ni] = *(const short8*)&lB[(wn * 64 + ni * 16 + l15) * 32 + lg * 8];
#pragma unroll
    for (int mi = 0; mi < 4; ++mi)
#pragma unroll
      for (int ni = 0; ni < 4; ++ni)
        acc[mi][ni] = MFMA_BF16(af[mi], bf[ni], acc[mi][ni]);
  }

  const int which = n0 >> 10;  // 0:Q 1:K 2:V  (n0 multiple of 128)
  const float* bias = (which == 0) ? bq : (which == 1) ? bk : bv;
#pragma unroll
  for (int ni = 0; ni < 4; ++ni) {
    const int n = n0 + wn * 64 + ni * 16 + l15;
    const int nn = n & 1023;
    const float bia = bias[nn];
    const int h = nn >> 6, hd = nn & 63;
#pragma unroll
    for (int mi = 0; mi < 4; ++mi) {
      const int mb = m0 + wm * 64 + mi * 16 + lg * 4;
      const int b = mb >> 11, s = mb & 2047;
      const int bh = b * 16 + h;
      if (which < 2) {
        unsigned short* dst = ((which == 0) ? qb : kb) + ((size_t)bh * 2048 + s) * 64 + hd;
#pragma unroll
        for (int r = 0; r < 4; ++r)
          dst[(size_t)r * 64] = f2bf(acc[mi][ni][r] + bia);
      } else {
        ushort4 pk;
        pk.x = f2bf(acc[mi][ni][0] + bia);
        pk.y = f2bf(acc[mi][ni][1] + bia);
        pk.z = f2bf(acc[mi][ni][2] + bia);
        pk.w = f2bf(acc[mi][ni][3] + bia);
        *(ushort4*)(vtb + ((size_t)bh * 64 + hd) * 2048 + s) = pk;
      }
    }
  }
}

// ---------------------------------------------------------------- flash attention
// Q,K: [bh][2048][64] bf16 ; VT: [bh][64][2048] bf16 ; out vals: [b*2048+s][1024] bf16
__global__ __launch_bounds__(256, 2) void attn_k(
    const unsigned short* __restrict__ Qb, const unsigned short* __restrict__ Kb,
    const unsigned short* __restrict__ VTb, const int* __restrict__ mask,
    unsigned short* __restrict__ vals) {
  __shared__ __align__(16) unsigned short Pl[4][32 * 72];
  const int tid = threadIdx.x;
  const int lane = tid & 63;
  const int w = tid >> 6;
  const int l15 = lane & 15, lg = lane >> 4;
  const int qt = blockIdx.x, bh = blockIdx.y;
  const int b = bh >> 4, h = bh & 15;
  const int q0 = qt * 128 + w * 32;
  const unsigned short* Qp = Qb + (size_t)bh * (2048 * 64);
  const unsigned short* Kp = Kb + (size_t)bh * (2048 * 64);
  const unsigned short* Vp = VTb + (size_t)bh * (64 * 2048);
  const int* mp = mask + b * 2048;
  unsigned short* Pw = Pl[w];

  short8 qf[2][2];
#pragma unroll
  for (int mi = 0; mi < 2; ++mi)
#pragma unroll
    for (int ks = 0; ks < 2; ++ks)
      qf[mi][ks] = *(const short8*)(Qp + (size_t)(q0 + mi * 16 + l15) * 64 + ks * 32 + lg * 8);

  const f32x4 zf = {0.0f, 0.0f, 0.0f, 0.0f};
  f32x4 acc[2][4];
  float mrun[2][4], lrun[2][4];
#pragma unroll
  for (int mi = 0; mi < 2; ++mi) {
#pragma unroll
    for (int hf = 0; hf < 4; ++hf) acc[mi][hf] = zf;
#pragma unroll
    for (int r = 0; r < 4; ++r) { mrun[mi][r] = -1e30f; lrun[mi][r] = 0.0f; }
  }

  for (int kv = 0; kv < 2048; kv += 64) {
    short8 kf[4][2], vf[4][2];
#pragma unroll
    for (int f = 0; f < 4; ++f) {
#pragma unroll
      for (int ks = 0; ks < 2; ++ks) {
        kf[f][ks] = *(const short8*)(Kp + (size_t)(kv + f * 16 + l15) * 64 + ks * 32 + lg * 8);
        vf[f][ks] = *(const short8*)(Vp + (size_t)(f * 16 + l15) * 2048 + kv + ks * 32 + lg * 8);
      }
    }
    int mv[4];
#pragma unroll
    for (int f = 0; f < 4; ++f) mv[f] = mp[kv + f * 16 + l15];

    f32x4 sc[2][4];
#pragma unroll
    for (int mi = 0; mi < 2; ++mi)
#pragma unroll
      for (int f = 0; f < 4; ++f) {
        f32x4 t = MFMA_BF16(qf[mi][0], kf[f][0], zf);
        sc[mi][f] = MFMA_BF16(qf[mi][1], kf[f][1], t);
      }
#pragma unroll
    for (int mi = 0; mi < 2; ++mi)
#pragma unroll
      for (int f = 0; f < 4; ++f)
#pragma unroll
        for (int r = 0; r < 4; ++r) {
          float sv = sc[mi][f][r] * 0.125f;
          sc[mi][f][r] = (mv[f] == 0) ? -3.0e38f : sv;
        }

    float rmax[2][4];
#pragma unroll
    for (int mi = 0; mi < 2; ++mi)
#pragma unroll
      for (int r = 0; r < 4; ++r)
        rmax[mi][r] = fmaxf(fmaxf(sc[mi][0][r], sc[mi][1][r]),
                            fmaxf(sc[mi][2][r], sc[mi][3][r]));
#pragma unroll
    for (int st = 1; st <= 8; st <<= 1)
#pragma unroll
      for (int mi = 0; mi < 2; ++mi)
#pragma unroll
        for (int r = 0; r < 4; ++r)
          rmax[mi][r] = fmaxf(rmax[mi][r], __shfl_xor(rmax[mi][r], st));

    float scl[2][4];
#pragma unroll
    for (int mi = 0; mi < 2; ++mi)
#pragma unroll
      for (int r = 0; r < 4; ++r) {
        float mn = fmaxf(mrun[mi][r], rmax[mi][r]);
        float s_ = __expf(mrun[mi][r] - mn);
        mrun[mi][r] = mn;
        lrun[mi][r] *= s_;
        scl[mi][r] = s_;
      }
#pragma unroll
    for (int mi = 0; mi < 2; ++mi)
#pragma unroll
      for (int hf = 0; hf < 4; ++hf)
#pragma unroll
        for (int r = 0; r < 4; ++r)
          acc[mi][hf][r] *= scl[mi][r];

    float rsum[2][4];
#pragma unroll
    for (int mi = 0; mi < 2; ++mi)
#pragma unroll
      for (int r = 0; r < 4; ++r) rsum[mi][r] = 0.0f;
#pragma unroll
    for (int mi = 0; mi < 2; ++mi)
#pragma unroll
      for (int f = 0; f < 4; ++f)
#pragma unroll
        for (int r = 0; r < 4; ++r) {
          float p = __expf(sc[mi][f][r] - mrun[mi][r]);
          rsum[mi][r] += p;
          Pw[(mi * 16 + lg * 4 + r) * 72 + f * 16 + l15] = f2bf(p);
        }
#pragma unroll
    for (int st = 1; st <= 8; st <<= 1)
#pragma unroll
      for (int mi = 0; mi < 2; ++mi)
#pragma unroll
        for (int r = 0; r < 4; ++r)
          rsum[mi][r] += __shfl_xor(rsum[mi][r], st);
#pragma unroll
    for (int mi = 0; mi < 2; ++mi)
#pragma unroll
      for (int r = 0; r < 4; ++r) lrun[mi][r] += rsum[mi][r];

    short8 pa[2][2];
#pragma unroll
    for (int mi = 0; mi < 2; ++mi)
#pragma unroll
      for (int ks = 0; ks < 2; ++ks)
        pa[mi][ks] = *(const short8*)&Pw[(mi * 16 + l15) * 72 + ks * 32 + lg * 8];
#pragma unroll
    for (int mi = 0; mi < 2; ++mi)
#pragma unroll
      for (int hf = 0; hf < 4; ++hf) {
        f32x4 t = MFMA_BF16(pa[mi][0], vf[hf][0], acc[mi][hf]);
        acc[mi][hf] = MFMA_BF16(pa[mi][1], vf[hf][1], t);
      }
  }

#pragma unroll
  for (int mi = 0; mi < 2; ++mi)
#pragma unroll
    for (int hf = 0; hf < 4; ++hf)
#pragma unroll
      for (int r = 0; r < 4; ++r) {
        float o = acc[mi][hf][r] / lrun[mi][r];
        int qr = q0 + mi * 16 + lg * 4 + r;
        vals[((size_t)b * 2048 + qr) * 1024 + h * 64 + hf * 16 + l15] = f2bf(o);
      }
}

// ---------------------------------------------------------------- GEMM2: output projection
__global__ __launch_bounds__(256, 2) void gemm_out_k(
    const unsigned short* __restrict__ A, const unsigned short* __restrict__ Bw,
    const float* __restrict__ bo, float* __restrict__ out) {
  const int K = 1024;
  __shared__ __align__(16) unsigned short lA[128 * 32];
  __shared__ __align__(16) unsigned short lB[128 * 32];
  const int tid = threadIdx.x;
  const int lane = tid & 63;
  const int w = tid >> 6;
  const int wm = w >> 1, wn = w & 1;
  const int m0 = blockIdx.x * 128, n0 = blockIdx.y * 128;
  const int l15 = lane & 15, lg = lane >> 4;

  const f32x4 zf = {0.0f, 0.0f, 0.0f, 0.0f};
  f32x4 acc[4][4];
#pragma unroll
  for (int mi = 0; mi < 4; ++mi)
#pragma unroll
    for (int ni = 0; ni < 4; ++ni) acc[mi][ni] = zf;

  const int c0 = tid, c1 = tid + 256;
  const int r0 = c0 >> 2, k0c = (c0 & 3) * 8;
  const int r1 = c1 >> 2, k1c = (c1 & 3) * 8;
  const unsigned short* ga0 = A + (size_t)(m0 + r0) * K + k0c;
  const unsigned short* ga1 = A + (size_t)(m0 + r1) * K + k1c;
  const unsigned short* gb0 = Bw + (size_t)(n0 + r0) * K + k0c;
  const unsigned short* gb1 = Bw + (size_t)(n0 + r1) * K + k1c;

  for (int kt = 0; kt < K; kt += 32) {
    short8 va0 = *(const short8*)(ga0 + kt);
    short8 va1 = *(const short8*)(ga1 + kt);
    short8 vb0 = *(const short8*)(gb0 + kt);
    short8 vb1 = *(const short8*)(gb1 + kt);
    __syncthreads();
    *(short8*)&lA[c0 * 8] = va0;
    *(short8*)&lA[c1 * 8] = va1;
    *(short8*)&lB[c0 * 8] = vb0;
    *(short8*)&lB[c1 * 8] = vb1;
    __syncthreads();
    short8 af[4], bf[4];
#pragma unroll
    for (int mi = 0; mi < 4; ++mi)
      af[mi] = *(const short8*)&lA[(wm * 64 + mi * 16 + l15) * 32 + lg * 8];
#pragma unroll
    for (int ni = 0; ni < 4; ++ni)
      bf[ni] = *(const short8*)&lB[(wn * 64 + ni * 16 + l15) * 32 + lg * 8];
#pragma unroll
    for (int mi = 0; mi < 4; ++mi)
#pragma unroll
      for (int ni = 0; ni < 4; ++ni)
        acc[mi][ni] = MFMA_BF16(af[mi], bf[ni], acc[mi][ni]);
  }

#pragma unroll
  for (int ni = 0; ni < 4; ++ni) {
    const int n = n0 + wn * 64 + ni * 16 + l15;
    const float bia = bo[n];
#pragma unroll
    for (int mi = 0; mi < 4; ++mi) {
      const int mb = m0 + wm * 64 + mi * 16 + lg * 4;
#pragma unroll
      for (int r = 0; r < 4; ++r)
        out[(size_t)(mb + r) * 1024 + n] = acc[mi][ni][r] + bia;
    }
  }
}

// ---------------------------------------------------------------- launch
extern "C" void kernel_launch(void* const* d_in, const int* in_sizes, int n_in,
                              void* d_out, int out_size, void* d_ws, size_t ws_size,
                              hipStream_t stream) {
  const float* x  = (const float*)d_in[0];
  const int* mask = (const int*)d_in[1];
  const float* Wq = (const float*)d_in[2];
  const float* bq = (const float*)d_in[3];
  const float* Wk = (const float*)d_in[4];
  const float* bk = (const float*)d_in[5];
  const float* Wv = (const float*)d_in[6];
  const float* bv = (const float*)d_in[7];
  const float* Wo = (const float*)d_in[8];
  const float* bo = (const float*)d_in[9];
  float* out = (float*)d_out;

  unsigned short* xb   = (unsigned short*)d_ws;            // 8192*1024
  unsigned short* wqkv = xb + (size_t)8192 * 1024;         // 3072*1024
  unsigned short* wob  = wqkv + (size_t)3072 * 1024;       // 1024*1024
  unsigned short* qb   = wob + (size_t)1024 * 1024;        // 64*2048*64
  unsigned short* kb   = qb + (size_t)64 * 2048 * 64;
  unsigned short* vtb  = kb + (size_t)64 * 2048 * 64;
  unsigned short* vals = vtb + (size_t)64 * 2048 * 64;     // 8192*1024

  convert_k<<<dim3(12288), dim3(256), 0, stream>>>(x, Wq, Wk, Wv, Wo, xb, wqkv, wob);
  gemm_qkv_k<<<dim3(64, 24), dim3(256), 0, stream>>>(xb, wqkv, bq, bk, bv, qb, kb, vtb);
  attn_k<<<dim3(16, 64), dim3(256), 0, stream>>>(qb, kb, vtb, mask, vals);
  gemm_out_k<<<dim3(64, 8), dim3(256), 0, stream>>>(vals, wob, bo, out);
}